// Round 4
// baseline (285.012 us; speedup 1.0000x reference)
//
#include <hip/hip_runtime.h>
#include <math.h>

// Problem constants
#define BN   32768
#define DIM  256
#define KC   1024
#define BN_EPS 1e-5f

// Output layout (floats) in d_out
#define QX_SIZE   (BN * DIM)
#define LOSS0_OFF (QX_SIZE)
#define LOSS1_OFF (QX_SIZE + 1)
#define IDX_OFF   (QX_SIZE + 2)
#define PERP_OFF  (QX_SIZE + 2 + BN)

// Workspace (float offsets)
#define WS_SUM    0     // 256
#define WS_SUMSQ  256   // 256
#define WS_COUNT  512   // 1
#define WS_LOSS   513   // 1
#define WS_COUNTS 1024  // 1024
#define WS_CNORM  3072  // 1024
#define WS_EBH    8192                  // bf16-hi frags, 131072 floats
#define WS_EBL    (8192 + 131072)       // bf16-lo frags, 131072 floats
#define WS_ETP    (8192 + 262144)       // eT [K][D] f32 when packed layout
#define WS_ET_LEG 8192                  // eT offset in legacy (small-ws) layout

typedef short bf16x8  __attribute__((ext_vector_type(8)));
typedef float f32x4   __attribute__((ext_vector_type(4)));
typedef float fvec4   __attribute__((ext_vector_type(4)));
typedef int   int4v   __attribute__((ext_vector_type(4)));

static __device__ inline unsigned short f2bf(float f) {
    unsigned int u = __float_as_uint(f);
    return (unsigned short)((u + 0x7FFFu + ((u >> 16) & 1u)) >> 16);
}
static __device__ inline fvec4 nt_ld4(const void* p) {
    return __builtin_nontemporal_load((const fvec4*)p);
}
static __device__ inline void nt_st(float* p, float v) {
    __builtin_nontemporal_store(v, p);
}

// ---------------------------------------------------------------- kernel 1
// Blocks 0..255: masked stats (128 rows each). 256..259: cnorm.
// 260..323: e -> eT transpose into ws + (use_pk) B-fragment bf16 pack.
__global__ __launch_bounds__(256) void k_pre(const float* __restrict__ x,
                                             const int* __restrict__ mask,
                                             const float* __restrict__ e,
                                             float* __restrict__ ws,
                                             int use_et, int use_pk, int et_off) {
    int t = threadIdx.x;
    int b = blockIdx.x;
    if (b >= 260) {                        // transpose tiles 64d x 64k
        if (!use_et) return;
        int b2 = b - 260;
        int d0 = (b2 >> 4) * 64;           // contraction (feature) rows
        int k0 = (b2 & 15) * 64;           // codes
        __shared__ float tile[64][65];
        int c = t & 63;
        int rq = t >> 6;
        #pragma unroll
        for (int p = 0; p < 16; ++p) {
            int dd = p * 4 + rq;
            tile[dd][c] = e[(size_t)(d0 + dd) * KC + k0 + c];
        }
        __syncthreads();
        #pragma unroll
        for (int p = 0; p < 16; ++p) {
            int kk = p * 4 + rq;
            nt_st(&ws[et_off + (size_t)(k0 + kk) * DIM + d0 + c], tile[c][kk]);
        }
        if (use_pk) {
            // pack 8 fragments (4 code-tiles x 2 k-chunks) from the tile.
            // Bit-identical to the in-loop truncate split of earlier rounds.
            short* pbh = (short*)(ws + WS_EBH);
            short* pbl = (short*)(ws + WS_EBL);
            int lane2 = t & 63;
            int g = t >> 6;                 // 0..3
            int quad2 = lane2 >> 4, col2 = lane2 & 15;
            #pragma unroll
            for (int f = 0; f < 2; ++f) {
                int fi = g * 2 + f;         // 0..7
                int ctl = fi >> 1, kcl = fi & 1;
                int ct = (b2 & 15) * 4 + ctl;       // code-tile 0..63
                int kc = (b2 >> 4) * 2 + kcl;       // k-chunk 0..7
                bf16x8 hv, lv;
                #pragma unroll
                for (int j = 0; j < 8; ++j) {
                    float v = tile[kcl * 32 + quad2 * 8 + j][ctl * 16 + col2];
                    unsigned u = __float_as_uint(v);
                    hv[j] = (short)(u >> 16);
                    float lf = v - __uint_as_float(u & 0xffff0000u);
                    lv[j] = (short)(__float_as_uint(lf) >> 16);
                }
                size_t fb = ((size_t)(ct * 8 + kc) * 64 + lane2) * 8;
                *(bf16x8*)(pbh + fb) = hv;
                *(bf16x8*)(pbl + fb) = lv;
            }
        }
        return;
    }
    if (b >= 256) {                        // cnorm
        int k = (b - 256) * 256 + t;
        float acc = 0.f;
        #pragma unroll 8
        for (int d = 0; d < DIM; ++d) {
            float v = e[(size_t)d * KC + k];
            acc = fmaf(v, v, acc);
        }
        ws[WS_CNORM + k] = acc;
        return;
    }
    __shared__ float s4[4 * 256];
    __shared__ float q4[4 * 256];
    __shared__ float cntS[4];
    int c4 = t & 63;
    int rsub = t >> 6;
    float s0=0.f,s1=0.f,s2=0.f,s3=0.f, q0=0.f,q1=0.f,q2=0.f,q3=0.f, cnt=0.f;
    int rbase = b * 4 + rsub;
    for (int i = 0; i < 32; ++i) {
        int r = rbase + i * 1024;
        float m = (float)mask[r];
        fvec4 v = nt_ld4(&x[(size_t)r * DIM + c4 * 4]);
        cnt += m;
        float m0 = m*v.x, m1 = m*v.y, m2 = m*v.z, m3 = m*v.w;
        s0 += m0; s1 += m1; s2 += m2; s3 += m3;
        q0 = fmaf(m0, v.x, q0); q1 = fmaf(m1, v.y, q1);
        q2 = fmaf(m2, v.z, q2); q3 = fmaf(m3, v.w, q3);
    }
    int f = c4 * 4;
    s4[rsub * 256 + f + 0] = s0; s4[rsub * 256 + f + 1] = s1;
    s4[rsub * 256 + f + 2] = s2; s4[rsub * 256 + f + 3] = s3;
    q4[rsub * 256 + f + 0] = q0; q4[rsub * 256 + f + 1] = q1;
    q4[rsub * 256 + f + 2] = q2; q4[rsub * 256 + f + 3] = q3;
    if (c4 == 0) cntS[rsub] = cnt;
    __syncthreads();
    float stot = s4[t] + s4[256 + t] + s4[512 + t] + s4[768 + t];
    float qtot = q4[t] + q4[256 + t] + q4[512 + t] + q4[768 + t];
    atomicAdd(&ws[WS_SUM + t], stot);
    atomicAdd(&ws[WS_SUMSQ + t], qtot);
    if (t == 0)
        atomicAdd(&ws[WS_COUNT], cntS[0] + cntS[1] + cntS[2] + cntS[3]);
}

// ---------------------------------------------------------------- kernel 3
// MFMA main. 256 threads (4 waves), 32 rows/block, grid 1024.
// acc[2][4] = 32 AGPRs; ~145 total regs -> (256,3) = 12 waves/CU;
// LDS ~40 KB -> 3 blocks/CU. Packed-B coalesced b128 + depth-1 prefetch.
// NO epilogue here (split into k_epi) — block ends after argmin + idx.
__global__ __launch_bounds__(256, 3) void k_main_mfma(
        const float* __restrict__ x, const int* __restrict__ mask,
        const float* __restrict__ e, const float* __restrict__ gamma,
        const float* __restrict__ beta,
        const float* __restrict__ ws, float* __restrict__ out, int use_pk) {
    __shared__ __align__(16) short afrag[8 * 2 * 2 * 64 * 8];   // 32 KB
    __shared__ float muS[DIM], scS[DIM], btS[DIM];
    __shared__ float cnS[KC];
    __shared__ float redv[32 * 4];
    __shared__ int   redi[32 * 4];

    const int tid = threadIdx.x;
    const int row0 = blockIdx.x * 32;
    const int w = tid >> 6;          // 0..3
    const int lane = tid & 63;
    const int quad = lane >> 4;
    const int col0 = lane & 15;

    {
        float cnt = ws[WS_COUNT];
        float nv = fmaxf(cnt, 1.f);
        float mu = ws[WS_SUM + tid] / nv;
        float var = ws[WS_SUMSQ + tid] / nv - mu * mu;
        var = fmaxf(var, 0.f);
        muS[tid] = mu;
        scS[tid] = rsqrtf(var + BN_EPS) * gamma[tid];
        btS[tid] = beta[tid];
    }
    #pragma unroll
    for (int p = 0; p < 4; ++p)
        cnS[p * 256 + tid] = ws[WS_CNORM + p * 256 + tid];
    __syncthreads();

    // ---- stage A-fragments: wave w stages mtile w>>1, kc-half w&1
    {
        const int mt = w >> 1;       // 0..1
        const float* xr = x + (size_t)(row0 + mt * 16 + col0) * DIM;
        const int kq = quad * 8;
        #pragma unroll
        for (int kk = 0; kk < 4; ++kk) {
            int kc = (w & 1) * 4 + kk;
            int k0 = kc * 32 + kq;
            fvec4 v0 = nt_ld4(xr + k0);
            fvec4 v1 = nt_ld4(xr + k0 + 4);
            float xv[8] = {v0.x, v0.y, v0.z, v0.w, v1.x, v1.y, v1.z, v1.w};
            bf16x8 hv, lv;
            #pragma unroll
            for (int j = 0; j < 8; ++j) {
                float xb = fmaf(xv[j] - muS[k0 + j], scS[k0 + j], btS[k0 + j]);
                unsigned short h = f2bf(xb);
                float hf = __uint_as_float((unsigned)h << 16);
                hv[j] = (short)h;
                lv[j] = (short)f2bf(xb - hf);
            }
            int base = (((kc * 2 + mt) * 2) * 64 + lane) * 8;
            *(bf16x8*)&afrag[base] = hv;
            *(bf16x8*)&afrag[base + 512] = lv;
        }
    }
    __syncthreads();

    f32x4 acc[2][4];
    #pragma unroll
    for (int mt = 0; mt < 2; ++mt)
        #pragma unroll
        for (int nt = 0; nt < 4; ++nt)
            acc[mt][nt] = (f32x4){0.f, 0.f, 0.f, 0.f};

    if (use_pk) {
        // ---------------- packed-fragment path ----------------
        const short* __restrict__ pbh = (const short*)(ws + WS_EBH);
        const short* __restrict__ pbl = (const short*)(ws + WS_EBL);
        // fragment base (shorts): ((ct*8+kc)*64+lane)*8, ct = w*16+ng*4+nt
        bf16x8 cbh[4], cbl[4], nbh[4], nbl[4];
        #pragma unroll
        for (int nt = 0; nt < 4; ++nt) {
            size_t fb = ((size_t)((w * 16 + nt) * 8) * 64 + lane) * 8;
            cbh[nt] = *(const bf16x8*)(pbh + fb);
            cbl[nt] = *(const bf16x8*)(pbl + fb);
        }
        #pragma unroll
        for (int ng = 0; ng < 4; ++ng) {
            #pragma unroll
            for (int kc = 0; kc < 8; ++kc) {
                const int ci = ng * 8 + kc;
                if (ci < 31) {
                    const int nci = ci + 1;
                    const int nng = nci >> 3, nkc = nci & 7;
                    #pragma unroll
                    for (int nt = 0; nt < 4; ++nt) {
                        size_t fb = ((size_t)((w * 16 + nng * 4 + nt) * 8 + nkc)
                                     * 64 + lane) * 8;
                        nbh[nt] = *(const bf16x8*)(pbh + fb);
                        nbl[nt] = *(const bf16x8*)(pbl + fb);
                    }
                }
                __builtin_amdgcn_sched_barrier(0);   // pin prefetch issue
                bf16x8 ah[2], al[2];
                #pragma unroll
                for (int mt = 0; mt < 2; ++mt) {
                    int base = (((kc * 2 + mt) * 2) * 64 + lane) * 8;
                    ah[mt] = *(const bf16x8*)&afrag[base];
                    al[mt] = *(const bf16x8*)&afrag[base + 512];
                }
                __builtin_amdgcn_s_setprio(1);
                #pragma unroll
                for (int nt = 0; nt < 4; ++nt) {
                    #pragma unroll
                    for (int mt = 0; mt < 2; ++mt) {
                        acc[mt][nt] = __builtin_amdgcn_mfma_f32_16x16x32_bf16(
                            ah[mt], cbh[nt], acc[mt][nt], 0, 0, 0);
                        acc[mt][nt] = __builtin_amdgcn_mfma_f32_16x16x32_bf16(
                            ah[mt], cbl[nt], acc[mt][nt], 0, 0, 0);
                        acc[mt][nt] = __builtin_amdgcn_mfma_f32_16x16x32_bf16(
                            al[mt], cbh[nt], acc[mt][nt], 0, 0, 0);
                    }
                }
                __builtin_amdgcn_s_setprio(0);
                if (ci < 31) {
                    #pragma unroll
                    for (int nt = 0; nt < 4; ++nt) {
                        cbh[nt] = nbh[nt];
                        cbl[nt] = nbl[nt];
                    }
                }
            }
            // end of ng: scores, in-wave butterfly argmin, merge to LDS
            #pragma unroll
            for (int mt = 0; mt < 2; ++mt) {
                #pragma unroll
                for (int r = 0; r < 4; ++r) {
                    float v = 3.4e38f; int ii = 0;
                    #pragma unroll
                    for (int nt = 0; nt < 4; ++nt) {
                        int kcode = w * 256 + ng * 64 + nt * 16 + col0;
                        float s = fmaf(-2.f, acc[mt][nt][r], cnS[kcode]);
                        if (s < v) { v = s; ii = kcode; }
                        acc[mt][nt][r] = 0.f;
                    }
                    #pragma unroll
                    for (int m2 = 1; m2 < 16; m2 <<= 1) {
                        float v2 = __shfl_xor(v, m2, 64);
                        int   i2 = __shfl_xor(ii, m2, 64);
                        if (v2 < v || (v2 == v && i2 < ii)) { v = v2; ii = i2; }
                    }
                    if (col0 == 0) {
                        int row = mt * 16 + quad * 4 + r;
                        if (ng == 0) {
                            redv[row * 4 + w] = v; redi[row * 4 + w] = ii;
                        } else {
                            float bvv = redv[row * 4 + w];
                            int   bii = redi[row * 4 + w];
                            if (v < bvv || (v == bvv && ii < bii)) {
                                redv[row * 4 + w] = v; redi[row * 4 + w] = ii;
                            }
                        }
                    }
                }
            }
        }
    } else {
        // ---------------- fallback: direct scattered loads from e ----------
        const float* ebase = e + quad * 8192 + w * 256 + col0;
        #pragma unroll
        for (int ng = 0; ng < 4; ++ng) {
            #pragma unroll
            for (int kc = 0; kc < 8; ++kc) {
                bf16x8 ah[2], al[2];
                #pragma unroll
                for (int mt = 0; mt < 2; ++mt) {
                    int base = (((kc * 2 + mt) * 2) * 64 + lane) * 8;
                    ah[mt] = *(const bf16x8*)&afrag[base];
                    al[mt] = *(const bf16x8*)&afrag[base + 512];
                }
                const float* ep = ebase + kc * 32768 + ng * 64;
                #pragma unroll
                for (int nt = 0; nt < 4; ++nt) {
                    const float* epn = ep + nt * 16;
                    float bv[8];
                    #pragma unroll
                    for (int j = 0; j < 8; ++j)
                        bv[j] = epn[j * 1024];
                    int4v hw, lw;
                    #pragma unroll
                    for (int p = 0; p < 4; ++p) {
                        unsigned u0 = __float_as_uint(bv[2 * p]);
                        unsigned u1 = __float_as_uint(bv[2 * p + 1]);
                        hw[p] = (int)__builtin_amdgcn_perm(u1, u0, 0x07060302u);
                        float l0 = bv[2 * p]     - __uint_as_float(u0 & 0xffff0000u);
                        float l1 = bv[2 * p + 1] - __uint_as_float(u1 & 0xffff0000u);
                        lw[p] = (int)__builtin_amdgcn_perm(__float_as_uint(l1),
                                                           __float_as_uint(l0),
                                                           0x07060302u);
                    }
                    bf16x8 bh = __builtin_bit_cast(bf16x8, hw);
                    bf16x8 bl = __builtin_bit_cast(bf16x8, lw);
                    #pragma unroll
                    for (int mt = 0; mt < 2; ++mt) {
                        acc[mt][nt] = __builtin_amdgcn_mfma_f32_16x16x32_bf16(
                            ah[mt], bh, acc[mt][nt], 0, 0, 0);
                        acc[mt][nt] = __builtin_amdgcn_mfma_f32_16x16x32_bf16(
                            ah[mt], bl, acc[mt][nt], 0, 0, 0);
                        acc[mt][nt] = __builtin_amdgcn_mfma_f32_16x16x32_bf16(
                            al[mt], bh, acc[mt][nt], 0, 0, 0);
                    }
                }
            }
            #pragma unroll
            for (int mt = 0; mt < 2; ++mt) {
                #pragma unroll
                for (int r = 0; r < 4; ++r) {
                    float v = 3.4e38f; int ii = 0;
                    #pragma unroll
                    for (int nt = 0; nt < 4; ++nt) {
                        int kcode = w * 256 + ng * 64 + nt * 16 + col0;
                        float s = fmaf(-2.f, acc[mt][nt][r], cnS[kcode]);
                        if (s < v) { v = s; ii = kcode; }
                        acc[mt][nt][r] = 0.f;
                    }
                    #pragma unroll
                    for (int m2 = 1; m2 < 16; m2 <<= 1) {
                        float v2 = __shfl_xor(v, m2, 64);
                        int   i2 = __shfl_xor(ii, m2, 64);
                        if (v2 < v || (v2 == v && i2 < ii)) { v = v2; ii = i2; }
                    }
                    if (col0 == 0) {
                        int row = mt * 16 + quad * 4 + r;
                        if (ng == 0) {
                            redv[row * 4 + w] = v; redi[row * 4 + w] = ii;
                        } else {
                            float bvv = redv[row * 4 + w];
                            int   bii = redi[row * 4 + w];
                            if (v < bvv || (v == bvv && ii < bii)) {
                                redv[row * 4 + w] = v; redi[row * 4 + w] = ii;
                            }
                        }
                    }
                }
            }
        }
    }
    __syncthreads();
    if (tid < 32) {
        float bv = redv[tid * 4];
        int bi = redi[tid * 4];
        #pragma unroll
        for (int t2 = 1; t2 < 4; ++t2) {
            float v = redv[tid * 4 + t2];
            int ii = redi[tid * 4 + t2];
            if (v < bv || (v == bv && ii < bi)) { bv = v; bi = ii; }
        }
        int m = mask[row0 + tid];
        out[IDX_OFF + row0 + tid] = m ? (float)bi : -1.0f;
        if (m) atomicAdd((float*)&ws[WS_COUNTS + bi], 1.0f);
    }
}

// ---------------------------------------------------------------- kernel 3b
// Streaming epilogue: recompute xb (fp32) from x, gather q from eT rows
// (coalesced), write quantized output + accumulate loss. Fully parallel,
// no MFMA-block coupling. 256 threads, 32 rows/block, grid 1024.
__global__ __launch_bounds__(256) void k_epi(
        const float* __restrict__ x, const int* __restrict__ mask,
        const float* __restrict__ e, const float* __restrict__ gamma,
        const float* __restrict__ beta,
        const float* __restrict__ ws, float* __restrict__ out,
        int use_et, int et_off) {
    __shared__ __align__(16) float muS[DIM], scS[DIM], btS[DIM];
    __shared__ float wred[4];
    const int tid = threadIdx.x;
    const int row0 = blockIdx.x * 32;
    const int w = tid >> 6;
    const int lane = tid & 63;
    {
        float cnt = ws[WS_COUNT];
        float nv = fmaxf(cnt, 1.f);
        float mu = ws[WS_SUM + tid] / nv;
        float var = ws[WS_SUMSQ + tid] / nv - mu * mu;
        var = fmaxf(var, 0.f);
        muS[tid] = mu;
        scS[tid] = rsqrtf(var + BN_EPS) * gamma[tid];
        btS[tid] = beta[tid];
    }
    __syncthreads();

    const int d0 = lane * 4;
    fvec4 mu4 = *(const fvec4*)&muS[d0];
    fvec4 sc4 = *(const fvec4*)&scS[d0];
    fvec4 bt4 = *(const fvec4*)&btS[d0];
    const float* et = ws + et_off;
    float lacc = 0.f;
    #pragma unroll
    for (int rr = 0; rr < 8; ++rr) {
        const int row = row0 + w * 8 + rr;
        const int m = mask[row];
        const float fm = (float)m;
        const int idx = m ? (int)out[IDX_OFF + row] : 0;
        fvec4 xv = nt_ld4(&x[(size_t)row * DIM + d0]);
        fvec4 g;
        if (use_et) {
            g = nt_ld4(&et[(size_t)idx * DIM + d0]);
        } else {
            g.x = e[(size_t)(d0 + 0) * KC + idx];
            g.y = e[(size_t)(d0 + 1) * KC + idx];
            g.z = e[(size_t)(d0 + 2) * KC + idx];
            g.w = e[(size_t)(d0 + 3) * KC + idx];
        }
        fvec4 q;
        float dsum = 0.f;
        #pragma unroll
        for (int i = 0; i < 4; ++i) {
            float xb = fmaf(xv[i] - mu4[i], sc4[i], bt4[i]);
            float diff = xb - g[i];
            dsum = fmaf(diff, diff, dsum);
            q[i] = fm * g[i];
        }
        lacc = fmaf(fm, dsum, lacc);
        __builtin_nontemporal_store(q, (fvec4*)&out[(size_t)row * DIM + d0]);
    }
    #pragma unroll
    for (int off2 = 32; off2 > 0; off2 >>= 1)
        lacc += __shfl_down(lacc, off2, 64);
    if (lane == 0) wred[w] = lacc;
    __syncthreads();
    if (tid == 0)
        atomicAdd((float*)&ws[WS_LOSS], wred[0] + wred[1] + wred[2] + wred[3]);
}

// ---------------------------------------------------------------- kernel 4
__global__ __launch_bounds__(256) void k_final(const float* __restrict__ ws,
                                               float* __restrict__ out) {
    int t = threadIdx.x;
    __shared__ float wr[4];
    float nv = fmaxf(ws[WS_COUNT], 1.f);
    float acc = 0.f;
    for (int j = t; j < KC; j += 256) {
        float p = ws[WS_COUNTS + j] / nv;
        acc = fmaf(p, logf(p + 1e-10f), acc);
    }
    #pragma unroll
    for (int off = 32; off > 0; off >>= 1) acc += __shfl_down(acc, off, 64);
    if ((t & 63) == 0) wr[t >> 6] = acc;
    __syncthreads();
    if (t == 0) {
        float ent = wr[0] + wr[1] + wr[2] + wr[3];
        float loss = ws[WS_LOSS] / (nv * (float)DIM);
        out[LOSS0_OFF] = loss;
        out[LOSS1_OFF] = loss;
        out[PERP_OFF] = expf(-ent);
    }
}

// ---------------------------------------------------------------- launch
extern "C" void kernel_launch(void* const* d_in, const int* in_sizes, int n_in,
                              void* d_out, int out_size, void* d_ws, size_t ws_size,
                              hipStream_t stream) {
    const float* x     = (const float*)d_in[0];
    const int*   amask = (const int*)d_in[1];
    const float* e     = (const float*)d_in[2];
    const float* gamma = (const float*)d_in[3];
    const float* beta  = (const float*)d_in[4];
    float* out = (float*)d_out;
    float* ws  = (float*)d_ws;

    size_t need_pk = (size_t)(WS_ETP + KC * DIM) * sizeof(float);    // ~2.03 MB
    size_t need_et = (size_t)(WS_ET_LEG + KC * DIM) * sizeof(float); // ~1.03 MB
    int use_pk = ws_size >= need_pk;
    int use_et = use_pk ? 1 : (ws_size >= need_et ? 1 : 0);
    int et_off = use_pk ? WS_ETP : WS_ET_LEG;

    (void)hipMemsetAsync(d_ws, 0, 8192, stream);

    k_pre<<<324, 256, 0, stream>>>(x, amask, e, ws, use_et, use_pk, et_off);
    k_main_mfma<<<BN / 32, 256, 0, stream>>>(x, amask, e, gamma, beta, ws, out,
                                             use_pk);
    k_epi<<<BN / 32, 256, 0, stream>>>(x, amask, e, gamma, beta, ws, out,
                                       use_et, et_off);
    k_final<<<1, 256, 0, stream>>>(ws, out);
}